// Round 2
// 274.259 us; speedup vs baseline: 1.0119x; 1.0119x over previous
//
#include <hip/hip_runtime.h>

#define IMAGE 224
#define PAD   30
#define CROP  164   // IMAGE - 2*PAD
#define BATCH 16
#define TT    16
#define W4    56    // IMAGE/4
#define HW4   (IMAGE * W4)        // 12544 float4s of one (b,c,t) image plane
#define BLOCKS_PER_BC 49          // HW4 / 256

// clang native vector type: required by __builtin_nontemporal_load/store
// (HIP's float4 is a struct and is rejected by the builtin).
typedef float f32x4 __attribute__((ext_vector_type(4)));

// One thread per (b,c,h,w4) float4 COLUMN of the output: the prompt value
// depends only on (b,c,h,w), so compute p[4] ONCE and stream all TT=16
// t-slices with independent, fully-unrolled nontemporal load+add+store.
// vs the 1-thread-per-float4 version this cuts the per-HBM-byte overhead
// (index math, divergent prompt branch, pad loads, cam/off loads) by 16x,
// while keeping perfect coalescing (contiguous 1KB per wave per iteration)
// and 16 independent memory chains per thread.
//
// b,c are block-uniform by construction (each (b,c) owns exactly 49 blocks),
// so cam_idx/off_right/off_down compile to scalar loads.
__global__ __launch_bounds__(256) void prompt_add_kernel(
    const float* __restrict__ x,
    const float* __restrict__ pu1,  const float* __restrict__ pu10,
    const float* __restrict__ pd1,  const float* __restrict__ pd10,
    const float* __restrict__ pl1,  const float* __restrict__ pl10,
    const float* __restrict__ pr1,  const float* __restrict__ pr10,
    const int* __restrict__ cam_idx,
    const int* __restrict__ off_right,
    const int* __restrict__ off_down,
    float* __restrict__ out)
{
    const int bid = blockIdx.x;
    const int b   = bid / (3 * BLOCKS_PER_BC);
    const int c   = (bid / BLOCKS_PER_BC) % 3;
    const int loc = (bid % BLOCKS_PER_BC) * 256 + threadIdx.x;  // 0..12543
    const int h   = loc / W4;
    const int w4  = loc % W4;

    const int ci    = cam_idx[b];
    const int orr   = off_right[b];
    const int od    = off_down[b];
    const int off_l = 2 * PAD - orr;
    const int off_u = 2 * PAD - od;
    const int n10_l = off_l / 10;
    const int n10_u = off_u / 10;
    const int n1_r  = orr % 10;
    const int n1_d  = od % 10;

    const int w0      = w4 * 4;
    const int base_cc = ci * 3 + c;   // camera*3 + channel

    float p0, p1, p2, p3;

    if (h < off_u) {
        // --- top band: row taken from pad_up_{10,1} (rows are 16B-aligned) ---
        const float* rowp = (h < n10_u * 10)
            ? (pu10 + (size_t)(base_cc * 10 + (h % 10)) * IMAGE)
            : (pu1  + (size_t)base_cc * IMAGE);
        const float4 pv = *reinterpret_cast<const float4*>(rowp + w0);
        p0 = pv.x; p1 = pv.y; p2 = pv.z; p3 = pv.w;
    } else if (h >= IMAGE - od) {
        // --- bottom band: row from pad_down_{1,10} ---
        const int hd = h - (IMAGE - od);          // >= 0
        const float* rowp = (hd < n1_d)
            ? (pd1  + (size_t)base_cc * IMAGE)
            : (pd10 + (size_t)(base_cc * 10 + ((hd - n1_d) % 10)) * IMAGE);
        const float4 pv = *reinterpret_cast<const float4*>(rowp + w0);
        p0 = pv.x; p1 = pv.y; p2 = pv.z; p3 = pv.w;
    } else {
        // --- middle band: left / zero / right per-w ---
        int r = h - off_u;
        r = r < 0 ? 0 : (r > CROP - 1 ? CROP - 1 : r);
        float p[4];
        #pragma unroll
        for (int j = 0; j < 4; ++j) {
            const int w = w0 + j;
            float v;
            if (w < off_l) {
                v = (w < n10_l * 10)
                    ? pl10[((size_t)base_cc * CROP + r) * 10 + (w % 10)]
                    : pl1 [ (size_t)base_cc * CROP + r];
            } else if (w >= IMAGE - orr) {
                const int wd = w - (IMAGE - orr);  // >= 0
                v = (wd < n1_r)
                    ? pr1 [ (size_t)base_cc * CROP + r]
                    : pr10[((size_t)base_cc * CROP + r) * 10 + ((wd - n1_r) % 10)];
            } else {
                v = 0.0f;
            }
            p[j] = v;
        }
        p0 = p[0]; p1 = p[1]; p2 = p[2]; p3 = p[3];
    }

    // --- stream all TT time slices: independent, unrolled, nontemporal ---
    const size_t plane  = (size_t)IMAGE * IMAGE;              // 50176 floats
    const size_t sbase  = ((size_t)(b * 3 + c) * TT) * plane
                        + (size_t)h * IMAGE + w0;             // 16B-aligned
    const float* xp = x   + sbase;
    float*       op = out + sbase;

    #pragma unroll
    for (int t = 0; t < TT; ++t) {
        const f32x4 xv = __builtin_nontemporal_load(
            reinterpret_cast<const f32x4*>(xp + (size_t)t * plane));
        f32x4 ov;
        ov.x = xv.x + p0;
        ov.y = xv.y + p1;
        ov.z = xv.z + p2;
        ov.w = xv.w + p3;
        __builtin_nontemporal_store(ov,
            reinterpret_cast<f32x4*>(op + (size_t)t * plane));
    }
}

extern "C" void kernel_launch(void* const* d_in, const int* in_sizes, int n_in,
                              void* d_out, int out_size, void* d_ws, size_t ws_size,
                              hipStream_t stream) {
    const float* x    = (const float*)d_in[0];
    const float* pu1  = (const float*)d_in[1];
    const float* pu10 = (const float*)d_in[2];
    const float* pd1  = (const float*)d_in[3];
    const float* pd10 = (const float*)d_in[4];
    const float* pl1  = (const float*)d_in[5];
    const float* pl10 = (const float*)d_in[6];
    const float* pr1  = (const float*)d_in[7];
    const float* pr10 = (const float*)d_in[8];
    const int* cam_idx   = (const int*)d_in[9];
    const int* off_right = (const int*)d_in[10];
    const int* off_down  = (const int*)d_in[11];
    float* out = (float*)d_out;

    const int grid  = BATCH * 3 * BLOCKS_PER_BC;  // 2352 blocks, exact cover
    const int block = 256;

    prompt_add_kernel<<<grid, block, 0, stream>>>(
        x, pu1, pu10, pd1, pd10, pl1, pl10, pr1, pr10,
        cam_idx, off_right, off_down, out);
}

// Round 3
// 273.966 us; speedup vs baseline: 1.0130x; 1.0011x over previous
//
#include <hip/hip_runtime.h>

#define IMAGE 224
#define PAD   30
#define CROP  164   // IMAGE - 2*PAD
#define BATCH 16
#define TT    16
#define W4    56    // IMAGE/4
#define HW4   (IMAGE * W4)        // 12544 float4s of one (b,c,t) image plane
#define BLOCKS_PER_BC 49          // HW4 / 256

// clang native vector type: required by __builtin_nontemporal_load/store
// (HIP's float4 is a struct and is rejected by the builtin).
typedef float f32x4 __attribute__((ext_vector_type(4)));

// One thread per (b,c,h,w4) float4 COLUMN: prompt p[4] computed once,
// then all TT=16 t-slices streamed.
//
// R2 change: EXPLICIT two-phase schedule — issue all 16 nontemporal loads
// first (64 data VGPRs, 16 independent HBM streams in flight), THEN do the
// 16 add+store. This forces the deep-pipelined copy schedule (stores drain
// with counted vmcnt(15..0)) instead of a per-iteration load->add->store
// chain that serializes on vmcnt(0) each plane. Discriminates hypothesis
// "kernel is waitcnt-serialized at ~3.4 TB/s" from "kernel already at BW
// roofline and dur_us is harness-fill dominated".
__global__ __launch_bounds__(256) void prompt_add_kernel(
    const float* __restrict__ x,
    const float* __restrict__ pu1,  const float* __restrict__ pu10,
    const float* __restrict__ pd1,  const float* __restrict__ pd10,
    const float* __restrict__ pl1,  const float* __restrict__ pl10,
    const float* __restrict__ pr1,  const float* __restrict__ pr10,
    const int* __restrict__ cam_idx,
    const int* __restrict__ off_right,
    const int* __restrict__ off_down,
    float* __restrict__ out)
{
    const int bid = blockIdx.x;
    const int b   = bid / (3 * BLOCKS_PER_BC);
    const int c   = (bid / BLOCKS_PER_BC) % 3;
    const int loc = (bid % BLOCKS_PER_BC) * 256 + threadIdx.x;  // 0..12543
    const int h   = loc / W4;
    const int w4  = loc % W4;

    const int ci    = cam_idx[b];
    const int orr   = off_right[b];
    const int od    = off_down[b];
    const int off_l = 2 * PAD - orr;
    const int off_u = 2 * PAD - od;
    const int n10_l = off_l / 10;
    const int n10_u = off_u / 10;
    const int n1_r  = orr % 10;
    const int n1_d  = od % 10;

    const int w0      = w4 * 4;
    const int base_cc = ci * 3 + c;   // camera*3 + channel

    float p0, p1, p2, p3;

    if (h < off_u) {
        // --- top band: row taken from pad_up_{10,1} (rows are 16B-aligned) ---
        const float* rowp = (h < n10_u * 10)
            ? (pu10 + (size_t)(base_cc * 10 + (h % 10)) * IMAGE)
            : (pu1  + (size_t)base_cc * IMAGE);
        const float4 pv = *reinterpret_cast<const float4*>(rowp + w0);
        p0 = pv.x; p1 = pv.y; p2 = pv.z; p3 = pv.w;
    } else if (h >= IMAGE - od) {
        // --- bottom band: row from pad_down_{1,10} ---
        const int hd = h - (IMAGE - od);          // >= 0
        const float* rowp = (hd < n1_d)
            ? (pd1  + (size_t)base_cc * IMAGE)
            : (pd10 + (size_t)(base_cc * 10 + ((hd - n1_d) % 10)) * IMAGE);
        const float4 pv = *reinterpret_cast<const float4*>(rowp + w0);
        p0 = pv.x; p1 = pv.y; p2 = pv.z; p3 = pv.w;
    } else {
        // --- middle band: left / zero / right per-w ---
        int r = h - off_u;
        r = r < 0 ? 0 : (r > CROP - 1 ? CROP - 1 : r);
        float p[4];
        #pragma unroll
        for (int j = 0; j < 4; ++j) {
            const int w = w0 + j;
            float v;
            if (w < off_l) {
                v = (w < n10_l * 10)
                    ? pl10[((size_t)base_cc * CROP + r) * 10 + (w % 10)]
                    : pl1 [ (size_t)base_cc * CROP + r];
            } else if (w >= IMAGE - orr) {
                const int wd = w - (IMAGE - orr);  // >= 0
                v = (wd < n1_r)
                    ? pr1 [ (size_t)base_cc * CROP + r]
                    : pr10[((size_t)base_cc * CROP + r) * 10 + ((wd - n1_r) % 10)];
            } else {
                v = 0.0f;
            }
            p[j] = v;
        }
        p0 = p[0]; p1 = p[1]; p2 = p[2]; p3 = p[3];
    }

    // --- stream all TT time slices, two-phase for max loads-in-flight ---
    const size_t plane  = (size_t)IMAGE * IMAGE;              // 50176 floats
    const size_t sbase  = ((size_t)(b * 3 + c) * TT) * plane
                        + (size_t)h * IMAGE + w0;             // 16B-aligned
    const float* xp = x   + sbase;
    float*       op = out + sbase;

    f32x4 xv[TT];
    #pragma unroll
    for (int t = 0; t < TT; ++t) {
        xv[t] = __builtin_nontemporal_load(
            reinterpret_cast<const f32x4*>(xp + (size_t)t * plane));
    }
    #pragma unroll
    for (int t = 0; t < TT; ++t) {
        f32x4 ov;
        ov.x = xv[t].x + p0;
        ov.y = xv[t].y + p1;
        ov.z = xv[t].z + p2;
        ov.w = xv[t].w + p3;
        __builtin_nontemporal_store(ov,
            reinterpret_cast<f32x4*>(op + (size_t)t * plane));
    }
}

extern "C" void kernel_launch(void* const* d_in, const int* in_sizes, int n_in,
                              void* d_out, int out_size, void* d_ws, size_t ws_size,
                              hipStream_t stream) {
    const float* x    = (const float*)d_in[0];
    const float* pu1  = (const float*)d_in[1];
    const float* pu10 = (const float*)d_in[2];
    const float* pd1  = (const float*)d_in[3];
    const float* pd10 = (const float*)d_in[4];
    const float* pl1  = (const float*)d_in[5];
    const float* pl10 = (const float*)d_in[6];
    const float* pr1  = (const float*)d_in[7];
    const float* pr10 = (const float*)d_in[8];
    const int* cam_idx   = (const int*)d_in[9];
    const int* off_right = (const int*)d_in[10];
    const int* off_down  = (const int*)d_in[11];
    float* out = (float*)d_out;

    const int grid  = BATCH * 3 * BLOCKS_PER_BC;  // 2352 blocks, exact cover
    const int block = 256;

    prompt_add_kernel<<<grid, block, 0, stream>>>(
        x, pu1, pu10, pd1, pd10, pl1, pl10, pr1, pr10,
        cam_idx, off_right, off_down, out);
}